// Round 7
// baseline (1184.270 us; speedup 1.0000x reference)
//
#include <hip/hip_runtime.h>

// 2-layer LSTM (H=50) + linear head — MFMA v3: 16-wave batch-half split.
//
// Round-6: 399 us, VALUBusy 68%, MfmaUtil 20% -> elementwise-VALU-bound with
// ~35% latency bubbles at 2 waves/SIMD. Fix: 16 waves (4/SIMD). Wave pairs
// sharing (layer, unit-block) duplicate the cheap MFMA but split the
// elementwise across accumulator row-halves (static indices, uniform branch).
// Also: exp-scale constants folded into the weight fragments:
//   i,f,o rows scaled by -log2e  -> sigmoid = rcp(1 + exp2(y))
//   g row scaled by +2*log2e     -> tanh    = 1 - 2*rcp(1 + exp2(y))
// (bias sits at k=52 inside the row, so it is scaled consistently for free).
//
// Wave wid (0..15): layer = wid>>3, sub = (wid>>2)&1 (acc-row half),
// ub = wid&3 (16-unit block). SIMD = wid&3 -> each SIMD hosts 2 L0 + 2 L1.
// K layout per batch (f16): [h0 0..49 | x 50,51 | 1.0 @52 | 0 | h1 64..113 |0]
// L0: K=64 (2 mfma/gate), L1: K=128 (4 mfma/gate). Weights = static
// B-fragments in registers. Double-buffered hc, 1 barrier/step, L1 lags 1.

typedef _Float16 f16;
typedef f16  f16x8 __attribute__((ext_vector_type(8)));
typedef float f32x4 __attribute__((ext_vector_type(4)));
typedef unsigned short u16;
typedef unsigned int   u32;

#define TT   512
#define MB   16     // batches per block (= MFMA M)
#define KP   136    // hc row length in f16 (128 + 8 pad)
#define XTP  513    // xpack row pad (column reads conflict-free)
#define BLK  1024   // 16 waves

#if __has_builtin(__builtin_amdgcn_exp2f)
#define EXP2(v) __builtin_amdgcn_exp2f(v)
#else
#define EXP2(v) __expf((v) * 0.6931471805599453f)   // same numerics, +1 mul
#endif
__device__ __forceinline__ float rcp_(float v) { return __builtin_amdgcn_rcpf(v); }

#define L2E  1.4426950408889634f
#define L2E2 2.8853900817779268f

// Weight element for B-fragment position (layer, gate g, out-unit u, k),
// pre-scaled: gates i,f,o (g=0,1,3) by -log2e; gate g (g=2) by +2*log2e.
__device__ __forceinline__ float welem(int layer, int g, int u, int k,
        const float* __restrict__ Wih0, const float* __restrict__ Whh0,
        const float* __restrict__ b0,
        const float* __restrict__ Wih1, const float* __restrict__ Whh1,
        const float* __restrict__ b1) {
    if (u >= 50) return 0.0f;
    const float s = (g == 2) ? L2E2 : -L2E;
    const int row = g * 50 + u;           // PyTorch gate order i,f,g,o
    if (layer == 0) {
        if (k < 50)  return s * Whh0[row * 50 + k];
        if (k < 52)  return s * Wih0[row * 2 + (k - 50)];
        if (k == 52) return s * b0[row];
        return 0.0f;
    } else {
        if (k < 50)             return s * Wih1[row * 50 + k];
        if (k == 52)            return s * b1[row];
        if (k >= 64 && k < 114) return s * Whh1[row * 50 + (k - 64)];
        return 0.0f;
    }
}

extern "C" __global__ void __launch_bounds__(BLK, 1)
lstm2_mfma16(const float* __restrict__ x,
             const float* __restrict__ W_ih0, const float* __restrict__ W_hh0,
             const float* __restrict__ b0,
             const float* __restrict__ W_ih1, const float* __restrict__ W_hh1,
             const float* __restrict__ b1,
             const float* __restrict__ W_fc,  const float* __restrict__ b_fc,
             float* __restrict__ out)
{
    __shared__ __align__(16) u16 hc[2][MB][KP];   // 8.7 KB double-buffered state
    __shared__ u32  xpack[MB][XTP];               // 32.8 KB, x as packed f16 pairs
    __shared__ float hfin[MB][52];                // final h1 (fp32) for the head

    const int tid   = threadIdx.x;
    const int lane  = tid & 63;
    const int wid   = tid >> 6;        // 0..15
    const int layer = wid >> 3;        // 0 or 1
    const int sub   = (wid >> 2) & 1;  // acc-row half (batch half)
    const int ub    = wid & 3;         // unit-block (16 units)
    const int col   = lane & 15;       // A-row (batch) / B-col (unit) / D-col
    const int kg    = lane >> 4;       // k-octet / D-row group
    const int bbase = blockIdx.x * MB;

    // ---- stage x -> packed f16 pairs in LDS (coalesced float2 loads) ----
    for (int idx = tid; idx < MB * TT; idx += BLK) {
        const int b = idx >> 9, t = idx & (TT - 1);
        const float2 v = *reinterpret_cast<const float2*>(
            x + ((size_t)(bbase + b) * TT + t) * 2);
        xpack[b][t] = (u32)__builtin_bit_cast(u16, (f16)v.x)
                    | ((u32)__builtin_bit_cast(u16, (f16)v.y) << 16);
    }
    // ---- zero hc (both buffers; pads stay 0 forever) ----
    {
        u32* hcU = reinterpret_cast<u32*>(&hc[0][0][0]);
        for (int i = tid; i < 2 * MB * KP / 2; i += BLK) hcU[i] = 0;
    }
    __syncthreads();
    // bias slot (k=52) = f16 1.0 in both buffers; x[0] into buffer 0
    if (tid < 32) hc[tid >> 4][tid & 15][52] = (u16)0x3C00;
    else if (tid < 48)
        *reinterpret_cast<u32*>(&hc[0][tid - 32][50]) = xpack[tid - 32][0];

    // ---- static weight B-fragments (constant-bound loops -> registers) ----
    // B map: lane l, elem e <-> B[k = kf*32 + 8*kg + e][n = col]; same
    // (lane,e)->k map as the A reads below, so in-octet permutations cancel.
    const int u = 16 * ub + col;
    f16x8 bf[4][4];    // [gate][kf]; L0 kf=2,3 all-zero (unused)
#pragma unroll
    for (int g = 0; g < 4; ++g) {
#pragma unroll
        for (int kf = 0; kf < 4; ++kf) {
            f16x8 v;
#pragma unroll
            for (int e = 0; e < 8; ++e)
                v[e] = (f16)welem(layer, g, u, kf * 32 + 8 * kg + e,
                                  W_ih0, W_hh0, b0, W_ih1, W_hh1, b1);
            bf[g][kf] = v;
        }
    }

    float c0 = 0.0f, c1 = 0.0f;        // cell state for this wave's 2 rows
    const int hbase = layer ? 64 : 0;
    __syncthreads();

    for (int it = 0; it <= TT; ++it) {
        const int p = it & 1, q = p ^ 1;

        // ===== phase 1: gates via MFMA =====
        // A map: lane l, elem e <-> hc[p][batch = col][k = kf*32 + 8*kg + e]
        f16x8 a[4];
#pragma unroll
        for (int kf = 0; kf < 4; ++kf)
            a[kf] = *reinterpret_cast<const f16x8*>(&hc[p][col][kf * 32 + 8 * kg]);

        f32x4 acc[4];
        const f32x4 z = {0.f, 0.f, 0.f, 0.f};
        if (layer == 0) {
#pragma unroll
            for (int g = 0; g < 4; ++g) {
                f32x4 c = __builtin_amdgcn_mfma_f32_16x16x32_f16(a[0], bf[g][0], z, 0, 0, 0);
                acc[g]  = __builtin_amdgcn_mfma_f32_16x16x32_f16(a[1], bf[g][1], c, 0, 0, 0);
            }
        } else {
#pragma unroll
            for (int g = 0; g < 4; ++g) {
                f32x4 c = __builtin_amdgcn_mfma_f32_16x16x32_f16(a[0], bf[g][0], z, 0, 0, 0);
                c       = __builtin_amdgcn_mfma_f32_16x16x32_f16(a[1], bf[g][1], c, 0, 0, 0);
                c       = __builtin_amdgcn_mfma_f32_16x16x32_f16(a[2], bf[g][2], c, 0, 0, 0);
                acc[g]  = __builtin_amdgcn_mfma_f32_16x16x32_f16(a[3], bf[g][3], c, 0, 0, 0);
            }
        }

        // ===== phase 2: elementwise, this wave's 2 acc rows only =====
        // D map (HW-verified): D[row = 4*kg + r][col]; row = batch, col = unit.
        // Pre-scaled gates: sigm = rcp(1+exp2(y)), tanh = 1-2*rcp(1+exp2(y)).
#define EWBODY(R, CS)                                                         \
        {                                                                     \
            const int bat = 4 * kg + (R);                                     \
            const float eI = EXP2(acc[0][R]);                                 \
            const float eF = EXP2(acc[1][R]);                                 \
            const float eG = EXP2(acc[2][R]);                                 \
            const float eO = EXP2(acc[3][R]);                                 \
            const float ig = rcp_(1.0f + eI);                                 \
            const float fg = rcp_(1.0f + eF);                                 \
            const float gg = fmaf(-2.0f, rcp_(1.0f + eG), 1.0f);              \
            const float og = rcp_(1.0f + eO);                                 \
            CS = fmaf(fg, CS, ig * gg);                                       \
            const float eC = EXP2(CS * L2E2);                                 \
            const float h  = og * fmaf(-2.0f, rcp_(1.0f + eC), 1.0f);         \
            hc[q][bat][hbase + u] = __builtin_bit_cast(u16, (f16)h);          \
            if (layer == 1 && it == TT) hfin[bat][u] = h;                     \
        }
        const bool ew = (layer == 0) ? (it < TT) : (it >= 1);
        if (ew && u < 50) {
            if (sub == 0) { EWBODY(0, c0) EWBODY(1, c1) }
            else          { EWBODY(2, c0) EWBODY(3, c1) }
        }
#undef EWBODY
        // next step's x into hc[q] slots 50,51
        if (wid == 0 && lane < MB && (it + 1) < TT)
            *reinterpret_cast<u32*>(&hc[q][lane][50]) = xpack[lane][it + 1];

        __syncthreads();
    }

    // ===== final linear head on fp32 h1[T-1] =====
    if (tid < MB) {
        float d = b_fc[0];
#pragma unroll
        for (int uu = 0; uu < 50; ++uu) d = fmaf(W_fc[uu], hfin[tid][uu], d);
        out[bbase + tid] = d;
    }
}

extern "C" void kernel_launch(void* const* d_in, const int* in_sizes, int n_in,
                              void* d_out, int out_size, void* d_ws, size_t ws_size,
                              hipStream_t stream) {
    const float* x     = (const float*)d_in[0];
    const float* W_ih0 = (const float*)d_in[1];
    const float* W_hh0 = (const float*)d_in[2];
    const float* b0    = (const float*)d_in[3];
    const float* W_ih1 = (const float*)d_in[4];
    const float* W_hh1 = (const float*)d_in[5];
    const float* b1    = (const float*)d_in[6];
    const float* W_fc  = (const float*)d_in[7];
    const float* b_fc  = (const float*)d_in[8];
    float* out = (float*)d_out;

    const int B = in_sizes[0] / (TT * 2);    // 4096
    dim3 grid(B / MB), block(BLK);           // 256 blocks = 1 per CU
    hipLaunchKernelGGL(lstm2_mfma16, grid, block, 0, stream,
                       x, W_ih0, W_hh0, b0, W_ih1, W_hh1, b1, W_fc, b_fc, out);
}

// Round 8
// 575.642 us; speedup vs baseline: 2.0573x; 2.0573x over previous
//
#include <hip/hip_runtime.h>

// 2-layer LSTM (H=50) + linear head — MFMA v4: K-split for 4 waves/SIMD.
//
// Round-7 failed: 16 waves => 128-reg/wave cap, L1 wave needed ~140 -> spill
// (WRITE_SIZE 13MB). Fix: every wave holds only HALF a K-row of weights
// (bf[4][2] = 32 VGPR):
//   L0 subs: full K=64 (kf 0,1), MFMA duplicated, elementwise rows split.
//   L1 subs: K split. sub0: kf{0,1} = W_ih1.h0 + bias; sub1: kf{2,3} =
//   W_hh1.h1. Partial gate sums exchanged via LDS (each sub writes the rows
//   it does NOT own, reads its own rows' partner-partials after a barrier).
// 16 waves: wid -> layer = wid>>3, sub = (wid>>2)&1, ub = wid&3.
// K layout per batch (f16): [h0 0..49 | x 50,51 | 1.0 @52 | 0 | h1 64..113 |0]
// Gate rows pre-scaled (i,f,o: -log2e; g: +2log2e; c-state kept 2log2e-scaled)
// so sigm = rcp(1+exp2(y)), tanh = 1-2*rcp(1+exp2(y)), no epilogue muls.
// Double-buffered hc; 2 barriers/step; L1 lags L0 by one step.

typedef _Float16 f16;
typedef f16  f16x8 __attribute__((ext_vector_type(8)));
typedef float f32x4 __attribute__((ext_vector_type(4)));
typedef unsigned short u16;
typedef unsigned int   u32;

#define TT   512
#define MB   16     // batches per block (= MFMA M)
#define KP   136    // hc row length in f16 (128 + 8 pad)
#define XTP  513    // xpack row pad (column reads conflict-free)
#define PU   53     // pbuf unit-dim pad (2-way bank alias = free)
#define BLK  1024   // 16 waves

#if __has_builtin(__builtin_amdgcn_exp2f)
#define EXP2(v) __builtin_amdgcn_exp2f(v)
#else
#define EXP2(v) __expf((v) * 0.6931471805599453f)
#endif
__device__ __forceinline__ float rcp_(float v) { return __builtin_amdgcn_rcpf(v); }

#define L2E  1.4426950408889634f
#define L2E2 2.8853900817779268f

// Weight element for B-fragment position (layer, gate g, out-unit u, k),
// pre-scaled: gates i,f,o (g=0,1,3) by -log2e; gate g (g=2) by +2*log2e.
__device__ __forceinline__ float welem(int layer, int g, int u, int k,
        const float* __restrict__ Wih0, const float* __restrict__ Whh0,
        const float* __restrict__ b0,
        const float* __restrict__ Wih1, const float* __restrict__ Whh1,
        const float* __restrict__ b1) {
    if (u >= 50) return 0.0f;
    const float s = (g == 2) ? L2E2 : -L2E;
    const int row = g * 50 + u;           // PyTorch gate order i,f,g,o
    if (layer == 0) {
        if (k < 50)  return s * Whh0[row * 50 + k];
        if (k < 52)  return s * Wih0[row * 2 + (k - 50)];
        if (k == 52) return s * b0[row];
        return 0.0f;
    } else {
        if (k < 50)             return s * Wih1[row * 50 + k];
        if (k == 52)            return s * b1[row];
        if (k >= 64 && k < 114) return s * Whh1[row * 50 + (k - 64)];
        return 0.0f;
    }
}

extern "C" __global__ void __launch_bounds__(BLK, 1)
lstm2_ksplit(const float* __restrict__ x,
             const float* __restrict__ W_ih0, const float* __restrict__ W_hh0,
             const float* __restrict__ b0,
             const float* __restrict__ W_ih1, const float* __restrict__ W_hh1,
             const float* __restrict__ b1,
             const float* __restrict__ W_fc,  const float* __restrict__ b_fc,
             float* __restrict__ out)
{
    __shared__ __align__(16) u16 hc[2][MB][KP];   // 8.7 KB double-buffered state
    __shared__ u32   xpack[MB][XTP];              // 32.8 KB packed f16 x pairs
    __shared__ float hfin[MB][52];                // final h1 (fp32) for the head
    __shared__ float pbuf[MB][4][PU];             // 13.6 KB L1 partial exchange

    const int tid   = threadIdx.x;
    const int lane  = tid & 63;
    const int wid   = tid >> 6;        // 0..15
    const int layer = wid >> 3;        // 0 or 1
    const int sub   = (wid >> 2) & 1;  // row-half / K-half selector
    const int ub    = wid & 3;         // unit-block (16 units)
    const int col   = lane & 15;       // A-row (batch) / B-col (unit) / D-col
    const int kg    = lane >> 4;       // k-octet / D-row group
    const int bbase = blockIdx.x * MB;

    // ---- stage x -> packed f16 pairs in LDS (coalesced float2 loads) ----
    for (int idx = tid; idx < MB * TT; idx += BLK) {
        const int b = idx >> 9, t = idx & (TT - 1);
        const float2 v = *reinterpret_cast<const float2*>(
            x + ((size_t)(bbase + b) * TT + t) * 2);
        xpack[b][t] = (u32)__builtin_bit_cast(u16, (f16)v.x)
                    | ((u32)__builtin_bit_cast(u16, (f16)v.y) << 16);
    }
    // ---- zero hc (both buffers; pads stay 0 forever) ----
    {
        u32* hcU = reinterpret_cast<u32*>(&hc[0][0][0]);
        for (int i = tid; i < 2 * MB * KP / 2; i += BLK) hcU[i] = 0;
    }
    __syncthreads();
    // bias slot (k=52) = f16 1.0 in both buffers; x[0] into buffer 0
    if (tid < 32) hc[tid >> 4][tid & 15][52] = (u16)0x3C00;
    else if (tid < 48)
        *reinterpret_cast<u32*>(&hc[0][tid - 32][50]) = xpack[tid - 32][0];

    // ---- static weight B-fragments: 2 kf per wave (32 VGPR) ----
    // L0: kf base 0 (full K=64). L1: kf base = 2*sub (K-half).
    // B map: lane l, elem e <-> B[k = (kb+j)*32 + 8*kg + e][n = col]; identical
    // (lane,e)->k map to the A reads -> in-octet permutations cancel.
    const int u  = 16 * ub + col;
    const int kb = (layer == 1 && sub == 1) ? 2 : 0;
    f16x8 bf[4][2];
#pragma unroll
    for (int g = 0; g < 4; ++g) {
#pragma unroll
        for (int j = 0; j < 2; ++j) {
            f16x8 v;
#pragma unroll
            for (int e = 0; e < 8; ++e)
                v[e] = (f16)welem(layer, g, u, (kb + j) * 32 + 8 * kg + e,
                                  W_ih0, W_hh0, b0, W_ih1, W_hh1, b1);
            bf[g][j] = v;
        }
    }

    float c0 = 0.0f, c1 = 0.0f;        // 2log2e-scaled cell state, 2 rows/wave
    const int hbase = layer ? 64 : 0;
    __syncthreads();

    for (int it = 0; it <= TT; ++it) {
        const int p = it & 1, q = p ^ 1;

        // ===== phase 1: (partial) gates via MFMA, K=64 per wave =====
        // A map: lane l, elem e <-> hc[p][batch = col][k = (kb+j)*32 + 8*kg + e]
        f16x8 a[2];
#pragma unroll
        for (int j = 0; j < 2; ++j)
            a[j] = *reinterpret_cast<const f16x8*>(&hc[p][col][(kb + j) * 32 + 8 * kg]);

        f32x4 acc[4];
        const f32x4 z = {0.f, 0.f, 0.f, 0.f};
#pragma unroll
        for (int g = 0; g < 4; ++g) {
            f32x4 c = __builtin_amdgcn_mfma_f32_16x16x32_f16(a[0], bf[g][0], z, 0, 0, 0);
            acc[g]  = __builtin_amdgcn_mfma_f32_16x16x32_f16(a[1], bf[g][1], c, 0, 0, 0);
        }

        // ===== phase 1b: L1 partial exchange (write rows NOT mine) =====
        if (layer == 1 && u < 50) {
            if (sub == 0) {
#pragma unroll
                for (int g = 0; g < 4; ++g) {
                    pbuf[4 * kg + 2][g][u] = acc[g][2];
                    pbuf[4 * kg + 3][g][u] = acc[g][3];
                }
            } else {
#pragma unroll
                for (int g = 0; g < 4; ++g) {
                    pbuf[4 * kg + 0][g][u] = acc[g][0];
                    pbuf[4 * kg + 1][g][u] = acc[g][1];
                }
            }
        }
        __syncthreads();

        // ===== phase 2: complete gates + elementwise on my 2 rows =====
        // D map (HW-verified): D[row = 4*kg + r][col]; row = batch, col = unit.
        // sigm = rcp(1+exp2(y)); tanh = 1-2*rcp(1+exp2(y)); c is 2log2e-scaled:
        // g-gate emitted as L2E2*tanh -> c' = f*c' + i*g'; tanh(c) = f(exp2(c')).
#define EWBODY(R, CS)                                                         \
        {                                                                     \
            const int bat = 4 * kg + (R);                                     \
            float yI = acc[0][R], yF = acc[1][R], yG = acc[2][R], yO = acc[3][R]; \
            if (layer == 1) {                                                 \
                yI += pbuf[bat][0][u]; yF += pbuf[bat][1][u];                 \
                yG += pbuf[bat][2][u]; yO += pbuf[bat][3][u];                 \
            }                                                                 \
            const float ig = rcp_(1.0f + EXP2(yI));                           \
            const float fg = rcp_(1.0f + EXP2(yF));                           \
            const float gs = fmaf(-2.0f * L2E2, rcp_(1.0f + EXP2(yG)), L2E2); \
            const float og = rcp_(1.0f + EXP2(yO));                           \
            CS = fmaf(fg, CS, ig * gs);                                       \
            const float h  = og * fmaf(-2.0f, rcp_(1.0f + EXP2(CS)), 1.0f);   \
            hc[q][bat][hbase + u] = __builtin_bit_cast(u16, (f16)h);          \
            if (layer == 1 && it == TT) hfin[bat][u] = h;                     \
        }
        const bool ew = (layer == 0) ? (it < TT) : (it >= 1);
        if (ew && u < 50) {
            if (sub == 0) { EWBODY(0, c0) EWBODY(1, c1) }
            else          { EWBODY(2, c0) EWBODY(3, c1) }
        }
#undef EWBODY
        // next step's x into hc[q] slots 50,51
        if (wid == 0 && lane < MB && (it + 1) < TT)
            *reinterpret_cast<u32*>(&hc[q][lane][50]) = xpack[lane][it + 1];

        __syncthreads();
    }

    // ===== final linear head on fp32 h1[T-1] =====
    if (tid < MB) {
        float d = b_fc[0];
#pragma unroll
        for (int uu = 0; uu < 50; ++uu) d = fmaf(W_fc[uu], hfin[tid][uu], d);
        out[bbase + tid] = d;
    }
}

extern "C" void kernel_launch(void* const* d_in, const int* in_sizes, int n_in,
                              void* d_out, int out_size, void* d_ws, size_t ws_size,
                              hipStream_t stream) {
    const float* x     = (const float*)d_in[0];
    const float* W_ih0 = (const float*)d_in[1];
    const float* W_hh0 = (const float*)d_in[2];
    const float* b0    = (const float*)d_in[3];
    const float* W_ih1 = (const float*)d_in[4];
    const float* W_hh1 = (const float*)d_in[5];
    const float* b1    = (const float*)d_in[6];
    const float* W_fc  = (const float*)d_in[7];
    const float* b_fc  = (const float*)d_in[8];
    float* out = (float*)d_out;

    const int B = in_sizes[0] / (TT * 2);    // 4096
    dim3 grid(B / MB), block(BLK);           // 256 blocks = 1 per CU
    hipLaunchKernelGGL(lstm2_ksplit, grid, block, 0, stream,
                       x, W_ih0, W_hh0, b0, W_ih1, W_hh1, b1, W_fc, b_fc, out);
}

// Round 9
// 400.459 us; speedup vs baseline: 2.9573x; 1.4375x over previous
//
#include <hip/hip_runtime.h>

// 2-layer LSTM (H=50) + linear head — MFMA v5: barrier-free gang pipeline.
//
// Round-8 lesson: the binder is BARRIER LOCKSTEP, not occupancy. All waves in
// phase => pipe bursts (MFMA idle during trans phase and vice versa) + slowest-
// wave wait, ~35-45% bubbles. Fix: keep round-6's dense 8-wave decomposition
// but remove __syncthreads from the step loop entirely:
//   L0 gang (waves 0-3) -> h0 into a 4-deep LDS ring, monotonic counter ctr0.
//   L1 gang (waves 4-7) -> h1 double-buffer, counter ctr1; consumes ring.
// Wave waits (volatile LDS spin + s_sleep):
//   L0 @s: ctr0 >= 4s (gang prev step), and before STORING: ctr1 >= 4(s-3)
//          (ring slot s%4 free of L1's step s-4 reads)  [s>=4 only]
//   L1 @t: ctr0 >= 4(t+1) (h0(t) ready), ctr1 >= 4t (own gang prev step)
// Deadlock-free: if L0 is 4 ahead it blocks but L1 can proceed; if level, L0
// proceeds. Gangs drift 1-4 steps => each SIMD's L0+L1 waves sit at different
// phases => MFMA/trans/LDS overlap across waves. All sync is LDS (CU-local).
//
// Also vs round 6: fused-rcp elementwise (8 trans/body instead of 10):
//   sigma via rcp(1+exp2(y)) with y pre-scaled by -log2e in the weights;
//   i*g' and o*tanh(c) each share ONE rcp; c kept in 2*log2e domain
//   (clamped +-80 before exp2 so the fused (e-1)*rcp((1+eO)(e+1)) never NaNs).
// s_setprio(1) around MFMA (role-split now exists for it to arbitrate).
//
// K layout per batch (f16): ring row = [h0 0..49 | x 50,51 | 1.0 @52 | 0 pad];
// h1 row = [h1 0..49 | 0 pad]. Rows RK=72 f16 = 144 B (16B-aligned reads,
// bank stride 4 => ~2-way, free). Weights = static B-frags in regs.

typedef _Float16 f16;
typedef f16  f16x8 __attribute__((ext_vector_type(8)));
typedef float f32x4 __attribute__((ext_vector_type(4)));
typedef unsigned short u16;
typedef unsigned int   u32;

#define TT   512
#define MB   16     // batches per block (= MFMA M)
#define RK   72     // ring/h1 row length in f16 (144 B)
#define XTP  513    // xpack row pad (column reads conflict-free)
#define BLK  512    // 8 waves

#define EXP2(v) __builtin_amdgcn_exp2f(v)
__device__ __forceinline__ float rcp_(float v) { return __builtin_amdgcn_rcpf(v); }

#define L2E  1.4426950408889634f
#define L2E2 2.8853900817779268f

// Weight element for B-fragment position (layer, gate g, out-unit u, k),
// pre-scaled: gates i,f,o (g=0,1,3) by -log2e; gate g (g=2) by +2*log2e.
__device__ __forceinline__ float welem(int layer, int g, int u, int k,
        const float* __restrict__ Wih0, const float* __restrict__ Whh0,
        const float* __restrict__ b0,
        const float* __restrict__ Wih1, const float* __restrict__ Whh1,
        const float* __restrict__ b1) {
    if (u >= 50) return 0.0f;
    const float s = (g == 2) ? L2E2 : -L2E;
    const int row = g * 50 + u;           // PyTorch gate order i,f,g,o
    if (layer == 0) {
        if (k < 50)  return s * Whh0[row * 50 + k];
        if (k < 52)  return s * Wih0[row * 2 + (k - 50)];
        if (k == 52) return s * b0[row];
        return 0.0f;
    } else {
        if (k < 50)             return s * Wih1[row * 50 + k];
        if (k == 52)            return s * b1[row];
        if (k >= 64 && k < 114) return s * Whh1[row * 50 + (k - 64)];
        return 0.0f;
    }
}

// Fused elementwise: inputs pre-scaled gate sums, cell state in L2E2 domain.
// sigma(z) = rcp(1 + exp2(-L2E*z)); i*g' = L2E2*(eG-1)*rcp((1+eI)(1+eG));
// h = o*tanh(c) = (eC-1)*rcp((1+eO)(eC+1)), eC = exp2(clamp(c',+-80)).
#define EWFUSED(YI, YF, YG, YO, CS, HOUT)                                     \
    {                                                                         \
        const float eI = EXP2(YI);                                            \
        const float eF = EXP2(YF);                                            \
        const float eG = EXP2(YG);                                            \
        const float eO = EXP2(YO);                                            \
        const float fg  = rcp_(1.0f + eF);                                    \
        const float num = fmaf(L2E2, eG, -L2E2);                              \
        const float igg = num * rcp_((1.0f + eI) * (1.0f + eG));              \
        CS = fmaf(fg, CS, igg);                                               \
        const float cc = fminf(fmaxf(CS, -80.0f), 80.0f);                     \
        const float eC = EXP2(cc);                                            \
        HOUT = (eC - 1.0f) * rcp_((1.0f + eO) * (eC + 1.0f));                 \
    }

extern "C" __global__ void __launch_bounds__(BLK, 2)
lstm2_async(const float* __restrict__ x,
            const float* __restrict__ W_ih0, const float* __restrict__ W_hh0,
            const float* __restrict__ b0,
            const float* __restrict__ W_ih1, const float* __restrict__ W_hh1,
            const float* __restrict__ b1,
            const float* __restrict__ W_fc,  const float* __restrict__ b_fc,
            float* __restrict__ out)
{
    __shared__ __align__(16) u16 ring[4][MB][RK];   // 9.2 KB h0 ring (+x,+bias)
    __shared__ __align__(16) u16 h1b[2][MB][RK];    // 4.6 KB h1 double buffer
    __shared__ u32   xpack[MB][XTP];                // 32.8 KB packed f16 x
    __shared__ float hfin[MB][52];                  // final h1 fp32 for head
    __shared__ u32   ctr0, ctr1;                    // gang progress counters

    const int tid   = threadIdx.x;
    const int lane  = tid & 63;
    const int wid   = tid >> 6;        // 0..7
    const int layer = wid >> 2;        // waves 0-3: L0 gang, 4-7: L1 gang
    const int ub    = wid & 3;         // unit-block (16 units)
    const int col   = lane & 15;       // A-row (batch) / B-col (unit) / D-col
    const int kg    = lane >> 4;       // k-octet / D-row group
    const int bbase = blockIdx.x * MB;

    // ---- stage x -> packed f16 pairs (coalesced float2 loads) ----
    for (int idx = tid; idx < MB * TT; idx += BLK) {
        const int b = idx >> 9, t = idx & (TT - 1);
        const float2 v = *reinterpret_cast<const float2*>(
            x + ((size_t)(bbase + b) * TT + t) * 2);
        xpack[b][t] = (u32)__builtin_bit_cast(u16, (f16)v.x)
                    | ((u32)__builtin_bit_cast(u16, (f16)v.y) << 16);
    }
    // ---- zero ring + h1b (pads stay 0 forever) ----
    {
        u32* p = reinterpret_cast<u32*>(&ring[0][0][0]);
        for (int i = tid; i < (int)(sizeof(ring) / 4); i += BLK) p[i] = 0;
        u32* q = reinterpret_cast<u32*>(&h1b[0][0][0]);
        for (int i = tid; i < (int)(sizeof(h1b) / 4); i += BLK) q[i] = 0;
    }
    if (tid == 0) { ctr0 = 0; ctr1 = 0; }
    __syncthreads();
    // bias slot k=52 (f16 1.0) in all 4 ring slots; x(0) into slot 3
    if (tid < 64) ring[tid >> 4][tid & 15][52] = (u16)0x3C00;
    else if (tid < 80)
        *reinterpret_cast<u32*>(&ring[3][tid - 64][50]) = xpack[tid - 64][0];

    // ---- static weight B-fragments (constant-bound loops -> registers) ----
    // B map: lane l, elem e <-> B[k = kf*32 + 8*kg + e][n = col]; identical
    // (lane,e)->k map as the A reads -> in-octet permutations cancel.
    const int u = 16 * ub + col;
    f16x8 bf[4][4];    // [gate][kf]; L0 kf=2,3 all-zero (unused)
#pragma unroll
    for (int g = 0; g < 4; ++g) {
#pragma unroll
        for (int kf = 0; kf < 4; ++kf) {
            f16x8 v;
#pragma unroll
            for (int e = 0; e < 8; ++e)
                v[e] = (f16)welem(layer, g, u, kf * 32 + 8 * kg + e,
                                  W_ih0, W_hh0, b0, W_ih1, W_hh1, b1);
            bf[g][kf] = v;
        }
    }

    __syncthreads();   // LAST barrier in the kernel

    volatile u32* vc0 = &ctr0;
    volatile u32* vc1 = &ctr1;
    float cst[4] = {0.f, 0.f, 0.f, 0.f};   // cell state (L2E2 domain)
    const f32x4 z = {0.f, 0.f, 0.f, 0.f};

    if (layer == 0) {
        // =================== L0 gang: free-running producer ===================
        for (int s = 0; s < TT; ++s) {
            while (*vc0 < (u32)(4 * s)) __builtin_amdgcn_s_sleep(1);
            const int rs = (s + 3) & 3, ws = s & 3;
            const f16x8 a0 = *reinterpret_cast<const f16x8*>(&ring[rs][col][8 * kg]);
            const f16x8 a1 = *reinterpret_cast<const f16x8*>(&ring[rs][col][32 + 8 * kg]);
            f32x4 acc[4];
            __builtin_amdgcn_s_setprio(1);
#pragma unroll
            for (int g = 0; g < 4; ++g) {
                f32x4 c = __builtin_amdgcn_mfma_f32_16x16x32_f16(a0, bf[g][0], z, 0, 0, 0);
                acc[g]  = __builtin_amdgcn_mfma_f32_16x16x32_f16(a1, bf[g][1], c, 0, 0, 0);
            }
            __builtin_amdgcn_s_setprio(0);
            u16 hw[4];
#pragma unroll
            for (int r = 0; r < 4; ++r) {
                float hv;
                EWFUSED(acc[0][r], acc[1][r], acc[2][r], acc[3][r], cst[r], hv);
                hw[r] = __builtin_bit_cast(u16, (f16)hv);
            }
            // ring slot s%4 must be free of L1's step s-4 reads
            if (s >= 4)
                while (*vc1 < (u32)(4 * (s - 3))) __builtin_amdgcn_s_sleep(1);
            if (u < 50) {
#pragma unroll
                for (int r = 0; r < 4; ++r) ring[ws][4 * kg + r][u] = hw[r];
            }
            if (wid == 0 && lane < MB && (s + 1) < TT)
                *reinterpret_cast<u32*>(&ring[ws][lane][50]) = xpack[lane][s + 1];
            __threadfence_block();
            if (lane == 0) atomicAdd(&ctr0, 1u);
        }
    } else {
        // =================== L1 gang: free-running consumer ===================
        for (int t = 0; t < TT; ++t) {
            while (*vc0 < (u32)(4 * (t + 1))) __builtin_amdgcn_s_sleep(1);
            while (*vc1 < (u32)(4 * t))       __builtin_amdgcn_s_sleep(1);
            const int rs = t & 3, wb = t & 1, rb = wb ^ 1;
            const f16x8 a0 = *reinterpret_cast<const f16x8*>(&ring[rs][col][8 * kg]);
            const f16x8 a1 = *reinterpret_cast<const f16x8*>(&ring[rs][col][32 + 8 * kg]);
            const f16x8 a2 = *reinterpret_cast<const f16x8*>(&h1b[rb][col][8 * kg]);
            const f16x8 a3 = *reinterpret_cast<const f16x8*>(&h1b[rb][col][32 + 8 * kg]);
            f32x4 acc[4];
            __builtin_amdgcn_s_setprio(1);
#pragma unroll
            for (int g = 0; g < 4; ++g) {
                f32x4 c = __builtin_amdgcn_mfma_f32_16x16x32_f16(a0, bf[g][0], z, 0, 0, 0);
                c       = __builtin_amdgcn_mfma_f32_16x16x32_f16(a1, bf[g][1], c, 0, 0, 0);
                c       = __builtin_amdgcn_mfma_f32_16x16x32_f16(a2, bf[g][2], c, 0, 0, 0);
                acc[g]  = __builtin_amdgcn_mfma_f32_16x16x32_f16(a3, bf[g][3], c, 0, 0, 0);
            }
            __builtin_amdgcn_s_setprio(0);
            u16 hw[4]; float hf[4];
#pragma unroll
            for (int r = 0; r < 4; ++r) {
                float hv;
                EWFUSED(acc[0][r], acc[1][r], acc[2][r], acc[3][r], cst[r], hv);
                hw[r] = __builtin_bit_cast(u16, (f16)hv);
                hf[r] = hv;
            }
            if (u < 50) {
#pragma unroll
                for (int r = 0; r < 4; ++r) h1b[wb][4 * kg + r][u] = hw[r];
                if (t == TT - 1) {
#pragma unroll
                    for (int r = 0; r < 4; ++r) hfin[4 * kg + r][u] = hf[r];
                }
            }
            __threadfence_block();
            if (lane == 0) atomicAdd(&ctr1, 1u);
        }
        // ---- final linear head on fp32 h1[T-1] (after whole L1 gang done) ----
        if (wid == 4) {
            while (*vc1 < (u32)(4 * TT)) __builtin_amdgcn_s_sleep(1);
            if (lane < MB) {
                float d = b_fc[0];
#pragma unroll
                for (int uu = 0; uu < 50; ++uu)
                    d = fmaf(W_fc[uu], hfin[lane][uu], d);
                out[bbase + lane] = d;
            }
        }
    }
}

extern "C" void kernel_launch(void* const* d_in, const int* in_sizes, int n_in,
                              void* d_out, int out_size, void* d_ws, size_t ws_size,
                              hipStream_t stream) {
    const float* x     = (const float*)d_in[0];
    const float* W_ih0 = (const float*)d_in[1];
    const float* W_hh0 = (const float*)d_in[2];
    const float* b0    = (const float*)d_in[3];
    const float* W_ih1 = (const float*)d_in[4];
    const float* W_hh1 = (const float*)d_in[5];
    const float* b1    = (const float*)d_in[6];
    const float* W_fc  = (const float*)d_in[7];
    const float* b_fc  = (const float*)d_in[8];
    float* out = (float*)d_out;

    const int B = in_sizes[0] / (TT * 2);    // 4096
    dim3 grid(B / MB), block(BLK);           // 256 blocks = 1 per CU
    hipLaunchKernelGGL(lstm2_async, grid, block, 0, stream,
                       x, W_ih0, W_hh0, b0, W_ih1, W_hh1, b1, W_fc, b_fc, out);
}

// Round 10
// 399.225 us; speedup vs baseline: 2.9664x; 1.0031x over previous
//
#include <hip/hip_runtime.h>

// 2-layer LSTM (H=50) + linear head — MFMA v5: barrier-free gang pipeline.
//
// Round-8 lesson: the binder is BARRIER LOCKSTEP, not occupancy. All waves in
// phase => pipe bursts (MFMA idle during trans phase and vice versa) + slowest-
// wave wait, ~35-45% bubbles. Fix: keep round-6's dense 8-wave decomposition
// but remove __syncthreads from the step loop entirely:
//   L0 gang (waves 0-3) -> h0 into a 4-deep LDS ring, monotonic counter ctr0.
//   L1 gang (waves 4-7) -> h1 double-buffer, counter ctr1; consumes ring.
// Wave waits (volatile LDS spin + s_sleep):
//   L0 @s: ctr0 >= 4s (gang prev step), and before STORING: ctr1 >= 4(s-3)
//          (ring slot s%4 free of L1's step s-4 reads)  [s>=4 only]
//   L1 @t: ctr0 >= 4(t+1) (h0(t) ready), ctr1 >= 4t (own gang prev step)
// Deadlock-free: if L0 is 4 ahead it blocks but L1 can proceed; if level, L0
// proceeds. Gangs drift 1-4 steps => each SIMD's L0+L1 waves sit at different
// phases => MFMA/trans/LDS overlap across waves. All sync is LDS (CU-local).
//
// Also vs round 6: fused-rcp elementwise (8 trans/body instead of 10):
//   sigma via rcp(1+exp2(y)) with y pre-scaled by -log2e in the weights;
//   i*g' and o*tanh(c) each share ONE rcp; c kept in 2*log2e domain
//   (clamped +-80 before exp2 so the fused (e-1)*rcp((1+eO)(e+1)) never NaNs).
// s_setprio(1) around MFMA (role-split now exists for it to arbitrate).
//
// K layout per batch (f16): ring row = [h0 0..49 | x 50,51 | 1.0 @52 | 0 pad];
// h1 row = [h1 0..49 | 0 pad]. Rows RK=72 f16 = 144 B (16B-aligned reads,
// bank stride 4 => ~2-way, free). Weights = static B-frags in regs.

typedef _Float16 f16;
typedef f16  f16x8 __attribute__((ext_vector_type(8)));
typedef float f32x4 __attribute__((ext_vector_type(4)));
typedef unsigned short u16;
typedef unsigned int   u32;

#define TT   512
#define MB   16     // batches per block (= MFMA M)
#define RK   72     // ring/h1 row length in f16 (144 B)
#define XTP  513    // xpack row pad (column reads conflict-free)
#define BLK  512    // 8 waves

#define EXP2(v) __builtin_amdgcn_exp2f(v)
__device__ __forceinline__ float rcp_(float v) { return __builtin_amdgcn_rcpf(v); }

#define L2E  1.4426950408889634f
#define L2E2 2.8853900817779268f

// Weight element for B-fragment position (layer, gate g, out-unit u, k),
// pre-scaled: gates i,f,o (g=0,1,3) by -log2e; gate g (g=2) by +2*log2e.
__device__ __forceinline__ float welem(int layer, int g, int u, int k,
        const float* __restrict__ Wih0, const float* __restrict__ Whh0,
        const float* __restrict__ b0,
        const float* __restrict__ Wih1, const float* __restrict__ Whh1,
        const float* __restrict__ b1) {
    if (u >= 50) return 0.0f;
    const float s = (g == 2) ? L2E2 : -L2E;
    const int row = g * 50 + u;           // PyTorch gate order i,f,g,o
    if (layer == 0) {
        if (k < 50)  return s * Whh0[row * 50 + k];
        if (k < 52)  return s * Wih0[row * 2 + (k - 50)];
        if (k == 52) return s * b0[row];
        return 0.0f;
    } else {
        if (k < 50)             return s * Wih1[row * 50 + k];
        if (k == 52)            return s * b1[row];
        if (k >= 64 && k < 114) return s * Whh1[row * 50 + (k - 64)];
        return 0.0f;
    }
}

// Fused elementwise: inputs pre-scaled gate sums, cell state in L2E2 domain.
// sigma(z) = rcp(1 + exp2(-L2E*z)); i*g' = L2E2*(eG-1)*rcp((1+eI)(1+eG));
// h = o*tanh(c) = (eC-1)*rcp((1+eO)(eC+1)), eC = exp2(clamp(c',+-80)).
#define EWFUSED(YI, YF, YG, YO, CS, HOUT)                                     \
    {                                                                         \
        const float eI = EXP2(YI);                                            \
        const float eF = EXP2(YF);                                            \
        const float eG = EXP2(YG);                                            \
        const float eO = EXP2(YO);                                            \
        const float fg  = rcp_(1.0f + eF);                                    \
        const float num = fmaf(L2E2, eG, -L2E2);                              \
        const float igg = num * rcp_((1.0f + eI) * (1.0f + eG));              \
        CS = fmaf(fg, CS, igg);                                               \
        const float cc = fminf(fmaxf(CS, -80.0f), 80.0f);                     \
        const float eC = EXP2(cc);                                            \
        HOUT = (eC - 1.0f) * rcp_((1.0f + eO) * (eC + 1.0f));                 \
    }

extern "C" __global__ void __launch_bounds__(BLK, 2)
lstm2_async(const float* __restrict__ x,
            const float* __restrict__ W_ih0, const float* __restrict__ W_hh0,
            const float* __restrict__ b0,
            const float* __restrict__ W_ih1, const float* __restrict__ W_hh1,
            const float* __restrict__ b1,
            const float* __restrict__ W_fc,  const float* __restrict__ b_fc,
            float* __restrict__ out)
{
    __shared__ __align__(16) u16 ring[4][MB][RK];   // 9.2 KB h0 ring (+x,+bias)
    __shared__ __align__(16) u16 h1b[2][MB][RK];    // 4.6 KB h1 double buffer
    __shared__ u32   xpack[MB][XTP];                // 32.8 KB packed f16 x
    __shared__ float hfin[MB][52];                  // final h1 fp32 for head
    __shared__ u32   ctr0, ctr1;                    // gang progress counters

    const int tid   = threadIdx.x;
    const int lane  = tid & 63;
    const int wid   = tid >> 6;        // 0..7
    const int layer = wid >> 2;        // waves 0-3: L0 gang, 4-7: L1 gang
    const int ub    = wid & 3;         // unit-block (16 units)
    const int col   = lane & 15;       // A-row (batch) / B-col (unit) / D-col
    const int kg    = lane >> 4;       // k-octet / D-row group
    const int bbase = blockIdx.x * MB;

    // ---- stage x -> packed f16 pairs (coalesced float2 loads) ----
    for (int idx = tid; idx < MB * TT; idx += BLK) {
        const int b = idx >> 9, t = idx & (TT - 1);
        const float2 v = *reinterpret_cast<const float2*>(
            x + ((size_t)(bbase + b) * TT + t) * 2);
        xpack[b][t] = (u32)__builtin_bit_cast(u16, (f16)v.x)
                    | ((u32)__builtin_bit_cast(u16, (f16)v.y) << 16);
    }
    // ---- zero ring + h1b (pads stay 0 forever) ----
    {
        u32* p = reinterpret_cast<u32*>(&ring[0][0][0]);
        for (int i = tid; i < (int)(sizeof(ring) / 4); i += BLK) p[i] = 0;
        u32* q = reinterpret_cast<u32*>(&h1b[0][0][0]);
        for (int i = tid; i < (int)(sizeof(h1b) / 4); i += BLK) q[i] = 0;
    }
    if (tid == 0) { ctr0 = 0; ctr1 = 0; }
    __syncthreads();
    // bias slot k=52 (f16 1.0) in all 4 ring slots; x(0) into slot 3
    if (tid < 64) ring[tid >> 4][tid & 15][52] = (u16)0x3C00;
    else if (tid < 80)
        *reinterpret_cast<u32*>(&ring[3][tid - 64][50]) = xpack[tid - 64][0];

    // ---- static weight B-fragments (constant-bound loops -> registers) ----
    // B map: lane l, elem e <-> B[k = kf*32 + 8*kg + e][n = col]; identical
    // (lane,e)->k map as the A reads -> in-octet permutations cancel.
    const int u = 16 * ub + col;
    f16x8 bf[4][4];    // [gate][kf]; L0 kf=2,3 all-zero (unused)
#pragma unroll
    for (int g = 0; g < 4; ++g) {
#pragma unroll
        for (int kf = 0; kf < 4; ++kf) {
            f16x8 v;
#pragma unroll
            for (int e = 0; e < 8; ++e)
                v[e] = (f16)welem(layer, g, u, kf * 32 + 8 * kg + e,
                                  W_ih0, W_hh0, b0, W_ih1, W_hh1, b1);
            bf[g][kf] = v;
        }
    }

    __syncthreads();   // LAST barrier in the kernel

    volatile u32* vc0 = &ctr0;
    volatile u32* vc1 = &ctr1;
    float cst[4] = {0.f, 0.f, 0.f, 0.f};   // cell state (L2E2 domain)
    const f32x4 z = {0.f, 0.f, 0.f, 0.f};

    if (layer == 0) {
        // =================== L0 gang: free-running producer ===================
        for (int s = 0; s < TT; ++s) {
            while (*vc0 < (u32)(4 * s)) __builtin_amdgcn_s_sleep(1);
            const int rs = (s + 3) & 3, ws = s & 3;
            const f16x8 a0 = *reinterpret_cast<const f16x8*>(&ring[rs][col][8 * kg]);
            const f16x8 a1 = *reinterpret_cast<const f16x8*>(&ring[rs][col][32 + 8 * kg]);
            f32x4 acc[4];
            __builtin_amdgcn_s_setprio(1);
#pragma unroll
            for (int g = 0; g < 4; ++g) {
                f32x4 c = __builtin_amdgcn_mfma_f32_16x16x32_f16(a0, bf[g][0], z, 0, 0, 0);
                acc[g]  = __builtin_amdgcn_mfma_f32_16x16x32_f16(a1, bf[g][1], c, 0, 0, 0);
            }
            __builtin_amdgcn_s_setprio(0);
            u16 hw[4];
#pragma unroll
            for (int r = 0; r < 4; ++r) {
                float hv;
                EWFUSED(acc[0][r], acc[1][r], acc[2][r], acc[3][r], cst[r], hv);
                hw[r] = __builtin_bit_cast(u16, (f16)hv);
            }
            // ring slot s%4 must be free of L1's step s-4 reads
            if (s >= 4)
                while (*vc1 < (u32)(4 * (s - 3))) __builtin_amdgcn_s_sleep(1);
            if (u < 50) {
#pragma unroll
                for (int r = 0; r < 4; ++r) ring[ws][4 * kg + r][u] = hw[r];
            }
            if (wid == 0 && lane < MB && (s + 1) < TT)
                *reinterpret_cast<u32*>(&ring[ws][lane][50]) = xpack[lane][s + 1];
            __threadfence_block();
            if (lane == 0) atomicAdd(&ctr0, 1u);
        }
    } else {
        // =================== L1 gang: free-running consumer ===================
        for (int t = 0; t < TT; ++t) {
            while (*vc0 < (u32)(4 * (t + 1))) __builtin_amdgcn_s_sleep(1);
            while (*vc1 < (u32)(4 * t))       __builtin_amdgcn_s_sleep(1);
            const int rs = t & 3, wb = t & 1, rb = wb ^ 1;
            const f16x8 a0 = *reinterpret_cast<const f16x8*>(&ring[rs][col][8 * kg]);
            const f16x8 a1 = *reinterpret_cast<const f16x8*>(&ring[rs][col][32 + 8 * kg]);
            const f16x8 a2 = *reinterpret_cast<const f16x8*>(&h1b[rb][col][8 * kg]);
            const f16x8 a3 = *reinterpret_cast<const f16x8*>(&h1b[rb][col][32 + 8 * kg]);
            f32x4 acc[4];
            __builtin_amdgcn_s_setprio(1);
#pragma unroll
            for (int g = 0; g < 4; ++g) {
                f32x4 c = __builtin_amdgcn_mfma_f32_16x16x32_f16(a0, bf[g][0], z, 0, 0, 0);
                c       = __builtin_amdgcn_mfma_f32_16x16x32_f16(a1, bf[g][1], c, 0, 0, 0);
                c       = __builtin_amdgcn_mfma_f32_16x16x32_f16(a2, bf[g][2], c, 0, 0, 0);
                acc[g]  = __builtin_amdgcn_mfma_f32_16x16x32_f16(a3, bf[g][3], c, 0, 0, 0);
            }
            __builtin_amdgcn_s_setprio(0);
            u16 hw[4]; float hf[4];
#pragma unroll
            for (int r = 0; r < 4; ++r) {
                float hv;
                EWFUSED(acc[0][r], acc[1][r], acc[2][r], acc[3][r], cst[r], hv);
                hw[r] = __builtin_bit_cast(u16, (f16)hv);
                hf[r] = hv;
            }
            if (u < 50) {
#pragma unroll
                for (int r = 0; r < 4; ++r) h1b[wb][4 * kg + r][u] = hw[r];
                if (t == TT - 1) {
#pragma unroll
                    for (int r = 0; r < 4; ++r) hfin[4 * kg + r][u] = hf[r];
                }
            }
            __threadfence_block();
            if (lane == 0) atomicAdd(&ctr1, 1u);
        }
        // ---- final linear head on fp32 h1[T-1] (after whole L1 gang done) ----
        if (wid == 4) {
            while (*vc1 < (u32)(4 * TT)) __builtin_amdgcn_s_sleep(1);
            if (lane < MB) {
                float d = b_fc[0];
#pragma unroll
                for (int uu = 0; uu < 50; ++uu)
                    d = fmaf(W_fc[uu], hfin[lane][uu], d);
                out[bbase + lane] = d;
            }
        }
    }
}

extern "C" void kernel_launch(void* const* d_in, const int* in_sizes, int n_in,
                              void* d_out, int out_size, void* d_ws, size_t ws_size,
                              hipStream_t stream) {
    const float* x     = (const float*)d_in[0];
    const float* W_ih0 = (const float*)d_in[1];
    const float* W_hh0 = (const float*)d_in[2];
    const float* b0    = (const float*)d_in[3];
    const float* W_ih1 = (const float*)d_in[4];
    const float* W_hh1 = (const float*)d_in[5];
    const float* b1    = (const float*)d_in[6];
    const float* W_fc  = (const float*)d_in[7];
    const float* b_fc  = (const float*)d_in[8];
    float* out = (float*)d_out;

    const int B = in_sizes[0] / (TT * 2);    // 4096
    dim3 grid(B / MB), block(BLK);           // 256 blocks = 1 per CU
    hipLaunchKernelGGL(lstm2_async, grid, block, 0, stream,
                       x, W_ih0, W_hh0, b0, W_ih1, W_hh1, b1, W_fc, b_fc, out);
}